// Round 8
// baseline (97.415 us; speedup 1.0000x reference)
//
#include <hip/hip_runtime.h>

// Chamfer distance, B=16, N=M=4096, D=3, fp32. memset + single kernel.
// d(i,j) = n_q + (n_t - 2 q.t).
// Each block stages 1024 targets (a quarter of the cloud) into 16 KB LDS,
// SoA pair-group format: group g = targets (2g,2g+1) as
// tA[g]=[x0,x1,y0,y1], tB[g]=[z0,z1,w0,w1] (w=|t|^2).
// Inner loop: 2 ds_read_b128 per group, amortized over 8 query-chains/lane
// (QPL=8). Query consts packed two-queries-per-VGPR-pair; v_pk_fma_f32
// op_sel broadcasts the lo/hi half -> 24 const VGPRs, no dup movs.
// Per (2 targets x query): 3 pk_fma + 1 min3. Blocks combine target
// quarters via uint atomicMin (valid for clamped non-negative fp32).

#define CB 16
#define CN 4096
#define CM 4096
#define WVS 8            // waves per block (512 threads)
#define QP2 4            // query PAIRS per lane (QPL = 8)
#define QPB 512          // queries per block
#define QRT_T 1024       // targets staged per block
#define GRPS 512         // pair-groups per block
#define GRP_PW 64        // groups per wave

typedef float v4f __attribute__((ext_vector_type(4)));
typedef float v2f __attribute__((ext_vector_type(2)));

// One pair-group (2 targets) vs query in LO half of the const pairs.
__device__ __forceinline__ void grp_lo(const v4f t0, const v4f t1,
                                       const v2f mx, const v2f my, const v2f mz,
                                       float& best)
{
    v2f d;
    asm("v_pk_fma_f32 %0, %1, %2, %3 op_sel:[0,0,0] op_sel_hi:[0,1,1]"
        : "=&v"(d) : "v"(mz), "v"(t1.xy), "v"(t1.zw));
    asm("v_pk_fma_f32 %0, %1, %2, %0 op_sel:[0,0,0] op_sel_hi:[0,1,1]"
        : "+v"(d) : "v"(my), "v"(t0.zw));
    asm("v_pk_fma_f32 %0, %1, %2, %0 op_sel:[0,0,0] op_sel_hi:[0,1,1]"
        : "+v"(d) : "v"(mx), "v"(t0.xy));
    asm("v_min3_f32 %0, %1, %2, %0" : "+v"(best) : "v"(d.x), "v"(d.y));
}

// Same, query in HI half of the const pairs.
__device__ __forceinline__ void grp_hi(const v4f t0, const v4f t1,
                                       const v2f mx, const v2f my, const v2f mz,
                                       float& best)
{
    v2f d;
    asm("v_pk_fma_f32 %0, %1, %2, %3 op_sel:[1,0,0] op_sel_hi:[1,1,1]"
        : "=&v"(d) : "v"(mz), "v"(t1.xy), "v"(t1.zw));
    asm("v_pk_fma_f32 %0, %1, %2, %0 op_sel:[1,0,0] op_sel_hi:[1,1,1]"
        : "+v"(d) : "v"(my), "v"(t0.zw));
    asm("v_pk_fma_f32 %0, %1, %2, %0 op_sel:[1,0,0] op_sel_hi:[1,1,1]"
        : "+v"(d) : "v"(mx), "v"(t0.xy));
    asm("v_min3_f32 %0, %1, %2, %0" : "+v"(best) : "v"(d.x), "v"(d.y));
}

// grid: (32 = 8 qtiles * 4 target-quarters, B, 2 dirs) = 1024 blocks.
__global__ __launch_bounds__(512, 8) void chamfer_min(
    const float* __restrict__ x1, const float* __restrict__ x2,
    float* __restrict__ out)
{
    const int dir    = blockIdx.z;
    const int b      = blockIdx.y;
    const int qtile  = blockIdx.x >> 2;
    const int tquart = blockIdx.x & 3;

    const float* __restrict__ qraw = (dir ? x2 : x1) + (size_t)b * CN * 3;
    const float* __restrict__ traw = (dir ? x1 : x2) + (size_t)b * CM * 3;
    float* __restrict__ o = out + (dir ? ((size_t)CB * CN + (size_t)b * CM)
                                       : ((size_t)b * CN));

    __shared__ v4f lds[GRPS * 2];            // 16 KB; red overlays after scan
    v4f* tA = lds;
    v4f* tB = lds + GRPS;
    float* red = (float*)lds;                // [WVS][8][64] = 16 KB

    const int tid  = threadIdx.x;
    const int lane = tid & 63;
    const int wave = __builtin_amdgcn_readfirstlane(tid >> 6);

    // ---- Stage: thread t packs group t (targets 2t, 2t+1). ----
    {
        const float* r = traw + ((size_t)tquart * QRT_T + 2 * (size_t)tid) * 3;
        v2f r01 = *(const v2f*)(r);        // x0,y0
        v2f r23 = *(const v2f*)(r + 2);    // z0,x1
        v2f r45 = *(const v2f*)(r + 4);    // y1,z1
        float w0 = fmaf(r01.x, r01.x, fmaf(r01.y, r01.y, r23.x * r23.x));
        float w1 = fmaf(r23.y, r23.y, fmaf(r45.x, r45.x, r45.y * r45.y));
        tA[tid] = (v4f){r01.x, r23.y, r01.y, r45.x};
        tB[tid] = (v4f){r23.x, r45.y, w0, w1};
    }

    // ---- Queries: 8/lane as 4 packed pairs (-2q in lo/hi halves). ----
    v2f mx2[QP2], my2[QP2], mz2[QP2];
    #pragma unroll
    for (int j = 0; j < QP2; ++j) {
        int q0 = qtile * QPB + lane + 128 * j;
        int q1 = q0 + 64;
        mx2[j] = (v2f){-2.0f * qraw[3 * q0 + 0], -2.0f * qraw[3 * q1 + 0]};
        my2[j] = (v2f){-2.0f * qraw[3 * q0 + 1], -2.0f * qraw[3 * q1 + 1]};
        mz2[j] = (v2f){-2.0f * qraw[3 * q0 + 2], -2.0f * qraw[3 * q1 + 2]};
    }

    float best[2 * QP2];
    #pragma unroll
    for (int k = 0; k < 2 * QP2; ++k) best[k] = 1e30f;

    __syncthreads();

    // ---- Scan: wave w owns groups [w*64, (w+1)*64), 2 groups/iter. ----
    const int gb = wave * GRP_PW;
    #pragma unroll 1
    for (int g = 0; g < GRP_PW; g += 2) {
        v4f a0 = tA[gb + g];
        v4f a1 = tB[gb + g];
        v4f b0 = tA[gb + g + 1];
        v4f b1 = tB[gb + g + 1];
        #pragma unroll
        for (int j = 0; j < QP2; ++j) {
            grp_lo(a0, a1, mx2[j], my2[j], mz2[j], best[2 * j]);
            grp_hi(a0, a1, mx2[j], my2[j], mz2[j], best[2 * j + 1]);
        }
        #pragma unroll
        for (int j = 0; j < QP2; ++j) {
            grp_lo(b0, b1, mx2[j], my2[j], mz2[j], best[2 * j]);
            grp_hi(b0, b1, mx2[j], my2[j], mz2[j], best[2 * j + 1]);
        }
    }

    __syncthreads();   // all reads done before red overlays lds

    // ---- Cross-wave combine; nq recomputed from consts. ----
    #pragma unroll
    for (int j = 0; j < QP2; ++j) {
        float nq0 = 0.25f * fmaf(mx2[j].x, mx2[j].x,
                           fmaf(my2[j].x, my2[j].x, mz2[j].x * mz2[j].x));
        float nq1 = 0.25f * fmaf(mx2[j].y, mx2[j].y,
                           fmaf(my2[j].y, my2[j].y, mz2[j].y * mz2[j].y));
        red[(wave * 8 + 2 * j) * 64 + lane]     = best[2 * j] + nq0;
        red[(wave * 8 + 2 * j + 1) * 64 + lane] = best[2 * j + 1] + nq1;
    }
    __syncthreads();

    {
        const int k = tid >> 6;      // query sub-index 0..7
        const int l = tid & 63;
        float v = red[k * 64 + l];
        #pragma unroll
        for (int w = 1; w < WVS; ++w)
            v = fminf(v, red[(w * 8 + k) * 64 + l]);
        // Clamped non-negative fp32: uint compare == float compare.
        atomicMin((unsigned int*)(o + qtile * QPB + tid),
                  __float_as_uint(fmaxf(v, 0.0f)));
    }
}

extern "C" void kernel_launch(void* const* d_in, const int* in_sizes, int n_in,
                              void* d_out, int out_size, void* d_ws, size_t ws_size,
                              hipStream_t stream) {
    const float* x1 = (const float*)d_in[0];   // [B,N,3]
    const float* x2 = (const float*)d_in[1];   // [B,M,3]
    float* out = (float*)d_out;

    // 0x7F7F7F7F = 3.39e38 > any clamped distance -> atomicMin always lands.
    hipMemsetAsync(out, 0x7F, (size_t)out_size * sizeof(float), stream);

    dim3 grid(32, CB, 2);
    chamfer_min<<<grid, 512, 0, stream>>>(x1, x2, out);
}